// Round 10
// baseline (932.701 us; speedup 1.0000x reference)
//
#include <hip/hip_runtime.h>
#include <hip/hip_bf16.h>

#define NN 100000
#define NE 3200000
#define DH 128
#define NL 3
#define NG 64
#define BN_EPS 1e-5f
#define NEG_INF (-1e30f)
#define BSH 9                 // bucket = 512 consecutive dst nodes
#define NB 196                // ceil(NN / 512)
#define EBLK 12800            // edges per k_bin block (NE = 250 * EBLK)
#define EBLK_H 3200           // edges per k_hist block (NE = 1000 * EBLK_H)
#define PSH 13                // src phase = src >> 13 (8192-node, 2MB chunks)
#define NPH 13                // ceil(NN / 8192)

typedef short bf16x8 __attribute__((ext_vector_type(8)));
typedef float f32x4  __attribute__((ext_vector_type(4)));

__device__ __forceinline__ void atomAddF(float* p, float v) {
    __hip_atomic_fetch_add(p, v, __ATOMIC_RELAXED, __HIP_MEMORY_SCOPE_AGENT);
}
__device__ __forceinline__ int atomAddI(int* p, int v) {
    return __hip_atomic_fetch_add(p, v, __ATOMIC_RELAXED, __HIP_MEMORY_SCOPE_AGENT);
}
// f32 -> bf16 round-to-nearest-even
__device__ __forceinline__ unsigned short bf16rn(float f) {
    unsigned int u = __float_as_uint(f);
    u += 0x7FFFu + ((u >> 16) & 1u);
    return (unsigned short)(u >> 16);
}
__device__ __forceinline__ float bf_lo(unsigned int u) { return __uint_as_float(u << 16); }
__device__ __forceinline__ float bf_hi(unsigned int u) { return __uint_as_float(u & 0xFFFF0000u); }
__device__ __forceinline__ float bfu(unsigned short u) {
    return __uint_as_float(((unsigned int)u) << 16);
}

__global__ void k_zero(int* __restrict__ bucketcnt, float* __restrict__ idsc,
                       float* __restrict__ psum) {
    int i = blockIdx.x * 256 + threadIdx.x;
    if (i < NB) bucketcnt[i] = 0;
    if (i < 2 * DH) idsc[i] = (i < DH) ? 1.0f : 0.0f;  // identity scale/shift
    if (i < NG * DH) psum[i] = 0.0f;
}

// one-time: x (f32) -> bf16 feature buffer
__global__ void k_convert(const float* __restrict__ X, ushort4* __restrict__ XB) {
    int i = blockIdx.x * 256 + threadIdx.x;
    if (i >= NN * DH / 4) return;
    float4 v = ((const float4*)X)[i];
    ushort4 o;
    o.x = bf16rn(v.x); o.y = bf16rn(v.y); o.z = bf16rn(v.z); o.w = bf16rn(v.w);
    XB[i] = o;
}

// one-time: W (f32 [l][k][n]) -> bf16 MFMA-fragment-contiguous pack:
// Wpack[l][ks][col][j] = W[l][ks*32+j][col]
__global__ void k_wconv(const float* __restrict__ W, unsigned short* __restrict__ WP) {
    int tid = blockIdx.x * 256 + threadIdx.x;
    if (tid >= NL * 16384) return;
    int l = tid >> 14;
    int p = tid & 16383;
    int ks = p >> 12;
    int col = (p >> 5) & 127;
    int j = p & 31;
    WP[tid] = bf16rn(W[l * 16384 + (ks * 32 + j) * 128 + col]);
}

// per-bucket edge histogram
__global__ __launch_bounds__(256) void k_hist(const int* __restrict__ dst,
                                              int* __restrict__ bucketcnt) {
    __shared__ int hist[NB];
    int t = threadIdx.x;
    if (t < NB) hist[t] = 0;
    __syncthreads();
    int base = blockIdx.x * EBLK_H;
    for (int i = t; i < EBLK_H; i += 256)
        atomicAdd(&hist[dst[base + i] >> BSH], 1);
    __syncthreads();
    if (t < NB && hist[t]) atomAddI(&bucketcnt[t], hist[t]);
}

// single block: exclusive scan of bucket counts
__global__ void k_scan(const int* __restrict__ bucketcnt, int* __restrict__ bucketoff,
                       int* __restrict__ gcursor) {
    __shared__ int s[256];
    int t = threadIdx.x;
    s[t] = (t < NB) ? bucketcnt[t] : 0;
    __syncthreads();
    for (int d = 1; d < 256; d <<= 1) {
        int v = (t >= d) ? s[t - d] : 0;
        __syncthreads();
        s[t] += v;
        __syncthreads();
    }
    if (t < NB) {
        int excl = s[t] - bucketcnt[t];
        bucketoff[t] = excl;
        gcursor[t] = excl;
    }
    if (t == NB - 1) bucketoff[NB] = s[t];
}

// bin edges into bucket-major order (one contiguous run reservation per bucket)
__global__ __launch_bounds__(256) void k_bin(const int* __restrict__ src,
        const int* __restrict__ dst, int* __restrict__ gcursor,
        uint2* __restrict__ tmp) {
    __shared__ int hist[NB], cur[NB];
    int t = threadIdx.x;
    if (t < NB) hist[t] = 0;
    __syncthreads();
    int base = blockIdx.x * EBLK;
    for (int i = t; i < EBLK; i += 256)
        atomicAdd(&hist[dst[base + i] >> BSH], 1);
    __syncthreads();
    if (t < NB) cur[t] = hist[t] ? atomAddI(&gcursor[t], hist[t]) : 0;
    __syncthreads();
    for (int i = t; i < EBLK; i += 256) {
        int d = dst[base + i], s = src[base + i];
        int pos = atomicAdd(&cur[d >> BSH], 1);
        tmp[pos] = make_uint2((unsigned)s, (unsigned)d);
    }
}

// one block per bucket: LDS histogram -> cnt/off/dinv; PHASED scatter so each
// node's edge list is ordered by src chunk (src>>13) -> aggregate's resident
// waves gather from a ~2MB window that fits per-XCD L2.
__global__ __launch_bounds__(512) void k_csr(const uint2* __restrict__ tmp,
        const int* __restrict__ bucketoff, int* __restrict__ cnt,
        float* __restrict__ dinv, int* __restrict__ off,
        int* __restrict__ edata) {
    __shared__ int lcnt[512];
    __shared__ int sc[512];
    int b = blockIdx.x, t = threadIdx.x;
    int nbase = b << BSH;
    int boff = bucketoff[b];
    int m = bucketoff[b + 1] - boff;
    lcnt[t] = 0;
    __syncthreads();
    for (int i = t; i < m; i += 512)
        atomicAdd(&lcnt[(int)tmp[boff + i].y - nbase], 1);
    __syncthreads();
    int c = lcnt[t];
    sc[t] = c;
    __syncthreads();
    for (int d = 1; d < 512; d <<= 1) {
        int v = (t >= d) ? sc[t - d] : 0;
        __syncthreads();
        sc[t] += v;
        __syncthreads();
    }
    int o = boff + sc[t] - c;
    int node = nbase + t;
    if (node < NN) {
        cnt[node] = c;
        off[node] = o;
        dinv[node] = rsqrtf((float)c + 1.0f);  // +1 self-loop
    }
    lcnt[t] = o;  // reuse as scatter cursor
    __syncthreads();
    for (int p = 0; p < NPH; ++p) {
        for (int i = t; i < m; i += 512) {
            uint2 r = tmp[boff + i];
            if ((int)(r.x >> PSH) == p) {
                int pos = atomicAdd(&lcnt[(int)r.y - nbase], 1);
                edata[pos] = (int)r.x;
            }
        }
        __syncthreads();
    }
}

__global__ void k_starts(const int* __restrict__ batch, int* __restrict__ starts) {
    int i = blockIdx.x * 256 + threadIdx.x;
    if (i >= NN) return;
    int g  = batch[i];
    int gp = (i == 0) ? -1 : batch[i - 1];
    for (int gg = gp + 1; gg <= g; ++gg) starts[gg] = i;
    if (i == NN - 1) {
        for (int gg = g + 1; gg <= NG; ++gg) starts[gg] = NN;
    }
}

// per-layer prepass: XD[s] = bf16( dinv[s] * relu(BN(Y[s])) ) -- hoists BN+ReLU
// +dinv out of aggregate's per-edge loop. Also zeroes stats for the next GEMM.
__global__ __launch_bounds__(256) void k_prep(const unsigned short* __restrict__ Y,
        const float* __restrict__ dinv, const float* __restrict__ SC, float lo,
        unsigned short* __restrict__ XD, float* __restrict__ stats) {
    int i = blockIdx.x * 256 + threadIdx.x;  // uint2 = 4 bf16 per thread
    if (blockIdx.x == 0 && threadIdx.x < 256) stats[threadIdx.x] = 0.0f;
    if (i >= NN * DH / 4) return;
    int row = i >> 5;
    int c4 = (i & 31) << 2;
    float di = dinv[row];
    uint2 u = ((const uint2*)Y)[i];
    float4 sc = *(const float4*)&SC[c4];
    float4 sh = *(const float4*)&SC[DH + c4];
    float f0 = di * fmaxf(fmaf(bf_lo(u.x), sc.x, sh.x), lo);
    float f1 = di * fmaxf(fmaf(bf_hi(u.x), sc.y, sh.y), lo);
    float f2 = di * fmaxf(fmaf(bf_lo(u.y), sc.z, sh.z), lo);
    float f3 = di * fmaxf(fmaf(bf_hi(u.y), sc.w, sh.w), lo);
    uint2 o;
    o.x = (unsigned int)bf16rn(f0) | ((unsigned int)bf16rn(f1) << 16);
    o.y = (unsigned int)bf16rn(f2) | ((unsigned int)bf16rn(f3) << 16);
    ((uint2*)XD)[i] = o;
}

// One wave per dst node: pure gather-add of XD rows (phase-ordered lists),
// S[d] = dinv[d] * (sum XD[src] + XD[d]), packed bf16 store.
__global__ __launch_bounds__(256) void k_aggregate(const unsigned short* __restrict__ XD,
        const int* __restrict__ ed, const int* __restrict__ off,
        const int* __restrict__ cnt, const float* __restrict__ dinv,
        unsigned short* __restrict__ SB) {
    int w = (blockIdx.x << 2) + (threadIdx.x >> 6);  // 4 waves/block
    if (w >= NN) return;
    int lane = threadIdx.x & 63;
    int o = __builtin_amdgcn_readfirstlane(off[w]);
    int n = __builtin_amdgcn_readfirstlane(cnt[w]);
    const int* e = ed + o;
    int col = lane << 1;
    float ax = 0.0f, ay = 0.0f;
    int j = 0;
    for (; j + 8 <= n; j += 8) {
        int s0 = e[j], s1 = e[j+1], s2 = e[j+2], s3 = e[j+3];
        int s4 = e[j+4], s5 = e[j+5], s6 = e[j+6], s7 = e[j+7];
        unsigned int u0 = *(const unsigned int*)&XD[(size_t)s0 * DH + col];
        unsigned int u1 = *(const unsigned int*)&XD[(size_t)s1 * DH + col];
        unsigned int u2 = *(const unsigned int*)&XD[(size_t)s2 * DH + col];
        unsigned int u3 = *(const unsigned int*)&XD[(size_t)s3 * DH + col];
        unsigned int u4 = *(const unsigned int*)&XD[(size_t)s4 * DH + col];
        unsigned int u5 = *(const unsigned int*)&XD[(size_t)s5 * DH + col];
        unsigned int u6 = *(const unsigned int*)&XD[(size_t)s6 * DH + col];
        unsigned int u7 = *(const unsigned int*)&XD[(size_t)s7 * DH + col];
        ax += bf_lo(u0); ay += bf_hi(u0);
        ax += bf_lo(u1); ay += bf_hi(u1);
        ax += bf_lo(u2); ay += bf_hi(u2);
        ax += bf_lo(u3); ay += bf_hi(u3);
        ax += bf_lo(u4); ay += bf_hi(u4);
        ax += bf_lo(u5); ay += bf_hi(u5);
        ax += bf_lo(u6); ay += bf_hi(u6);
        ax += bf_lo(u7); ay += bf_hi(u7);
    }
    for (; j < n; ++j) {
        unsigned int u0 = *(const unsigned int*)&XD[(size_t)e[j] * DH + col];
        ax += bf_lo(u0); ay += bf_hi(u0);
    }
    unsigned int us = *(const unsigned int*)&XD[(size_t)w * DH + col];
    float di = dinv[w];
    float ox = di * (ax + bf_lo(us));
    float oy = di * (ay + bf_hi(us));
    unsigned int up = (unsigned int)bf16rn(ox) | ((unsigned int)bf16rn(oy) << 16);
    *(unsigned int*)&SB[(size_t)w * DH + col] = up;
}

// MFMA GEMM: Y = S(bf16) @ W(bf16), f32 accum; bf16 out + BN stats.
__global__ __launch_bounds__(256) void k_gemm_mfma(const unsigned short* __restrict__ A,
        const unsigned short* __restrict__ WP, unsigned short* __restrict__ YB,
        float* __restrict__ stats) {
    __shared__ unsigned short ctile[128 * 132];  // 33 KB
    int t = threadIdx.x;
    int lane = t & 63, wid = t >> 6;
    int wr = wid >> 1, wc = wid & 1;
    int lr = lane & 15, lg = lane >> 4;
    int row0 = blockIdx.x * 128;
    f32x4 acc[4][4] = {};
#pragma unroll
    for (int ks = 0; ks < 4; ++ks) {
        bf16x8 a[4], b[4];
        const unsigned short* abase =
            A + (size_t)(row0 + wr * 64 + lr) * DH + ks * 32 + lg * 8;
#pragma unroll
        for (int rb = 0; rb < 4; ++rb)
            a[rb] = *(const bf16x8*)(abase + (size_t)rb * 16 * DH);
        const unsigned short* bbase = WP + ks * 4096 + (wc * 64 + lr) * 32 + lg * 8;
#pragma unroll
        for (int cb = 0; cb < 4; ++cb)
            b[cb] = *(const bf16x8*)(bbase + cb * 16 * 32);
#pragma unroll
        for (int rb = 0; rb < 4; ++rb)
#pragma unroll
            for (int cb = 0; cb < 4; ++cb)
                acc[rb][cb] = __builtin_amdgcn_mfma_f32_16x16x32_bf16(
                    a[rb], b[cb], acc[rb][cb], 0, 0, 0);
    }
    // C/D layout: col = lane&15, row = (lane>>4)*4 + reg
#pragma unroll
    for (int rb = 0; rb < 4; ++rb)
#pragma unroll
        for (int cb = 0; cb < 4; ++cb)
#pragma unroll
            for (int r = 0; r < 4; ++r) {
                int row = wr * 64 + rb * 16 + lg * 4 + r;
                int col = wc * 64 + cb * 16 + lr;
                ctile[row * 132 + col] = bf16rn(acc[rb][cb][r]);
            }
    __syncthreads();
    int c4 = (t & 31) << 2;
    int r0l = t >> 5;
    float ps[4] = {}, q[4] = {};
#pragma unroll
    for (int i = 0; i < 16; ++i) {
        int rl = r0l + (i << 3);
        int r = row0 + rl;
        if (r < NN) {
            ushort4 v = *(const ushort4*)&ctile[rl * 132 + c4];
            *(ushort4*)&YB[(size_t)r * DH + c4] = v;
            float f0 = bfu(v.x), f1 = bfu(v.y), f2 = bfu(v.z), f3 = bfu(v.w);
            ps[0] += f0; ps[1] += f1; ps[2] += f2; ps[3] += f3;
            q[0] = fmaf(f0, f0, q[0]); q[1] = fmaf(f1, f1, q[1]);
            q[2] = fmaf(f2, f2, q[2]); q[3] = fmaf(f3, f3, q[3]);
        }
    }
    __syncthreads();  // ctile dead; reuse as reduction scratch
    float* red = (float*)ctile;
    int base = t * 8;
    red[base + 0] = ps[0]; red[base + 1] = ps[1]; red[base + 2] = ps[2]; red[base + 3] = ps[3];
    red[base + 4] = q[0];  red[base + 5] = q[1];  red[base + 6] = q[2];  red[base + 7] = q[3];
    __syncthreads();
    if (t < 32) {
        float s[8] = {};
        for (int g2 = 0; g2 < 8; ++g2) {
            int b2 = (g2 * 32 + t) * 8;
#pragma unroll
            for (int j = 0; j < 8; ++j) s[j] += red[b2 + j];
        }
        int cc = t << 2;
        atomAddF(&stats[cc + 0], s[0]); atomAddF(&stats[cc + 1], s[1]);
        atomAddF(&stats[cc + 2], s[2]); atomAddF(&stats[cc + 3], s[3]);
        atomAddF(&stats[DH + cc + 0], s[4]); atomAddF(&stats[DH + cc + 1], s[5]);
        atomAddF(&stats[DH + cc + 2], s[6]); atomAddF(&stats[DH + cc + 3], s[7]);
    }
}

// stats -> per-channel scale/shift for fused BN
__global__ void k_bnprep(const float* __restrict__ stats, const float* __restrict__ gamma,
                         const float* __restrict__ beta, float* __restrict__ SC) {
    int j = threadIdx.x;
    if (j >= DH) return;
    const float inv_n = 1.0f / NN;
    float mean = stats[j] * inv_n;
    float var  = stats[DH + j] * inv_n - mean * mean;
    float s    = gamma[j] * rsqrtf(var + BN_EPS);
    SC[j] = s;
    SC[DH + j] = beta[j] - mean * s;
}

// Parallel pool over bf16 features: BN+ReLU inline; atomic flush at graph
// boundaries only (batch sorted).
__global__ __launch_bounds__(128) void k_pool_partial(const unsigned short* __restrict__ HB,
        const int* __restrict__ batch, const float* __restrict__ SC,
        float* __restrict__ psum) {
    __shared__ int bsh[128];
    int t = threadIdx.x;
    int row0 = blockIdx.x * 128;
    int rl = row0 + t;
    bsh[t] = batch[rl < NN ? rl : (NN - 1)];
    __syncthreads();
    int ro = t >> 5;
    int c  = (t & 31) << 2;
    float4 sc = *(const float4*)&SC[c];
    float4 sh = *(const float4*)&SC[DH + c];
    int nrows = NN - row0; if (nrows > 128) nrows = 128;
    float4 acc = make_float4(0.f, 0.f, 0.f, 0.f);
    int cur = -1;
    for (int rr = ro; rr < nrows; rr += 4) {
        int g = bsh[rr];
        if (g != cur) {
            if (cur >= 0) {
                float* p = &psum[(cur << 7) + c];
                atomAddF(p + 0, acc.x); atomAddF(p + 1, acc.y);
                atomAddF(p + 2, acc.z); atomAddF(p + 3, acc.w);
            }
            acc = make_float4(0.f, 0.f, 0.f, 0.f);
            cur = g;
        }
        uint2 u = *(const uint2*)&HB[(size_t)(row0 + rr) * DH + c];
        acc.x += fmaxf(fmaf(bf_lo(u.x), sc.x, sh.x), 0.0f);
        acc.y += fmaxf(fmaf(bf_hi(u.x), sc.y, sh.y), 0.0f);
        acc.z += fmaxf(fmaf(bf_lo(u.y), sc.z, sh.z), 0.0f);
        acc.w += fmaxf(fmaf(bf_hi(u.y), sc.w, sh.w), 0.0f);
    }
    if (cur >= 0) {
        float* p = &psum[(cur << 7) + c];
        atomAddF(p + 0, acc.x); atomAddF(p + 1, acc.y);
        atomAddF(p + 2, acc.z); atomAddF(p + 3, acc.w);
    }
}

// One block per graph: divide by count, hidden GEMV, reduce to scalar output.
__global__ __launch_bounds__(128) void k_mlp(const float* __restrict__ psum,
        const int* __restrict__ starts, const float* __restrict__ w1,
        const float* __restrict__ b1, const float* __restrict__ w2,
        const float* __restrict__ b2, float* __restrict__ out) {
    __shared__ float pl[DH];
    __shared__ float red[DH];
    int g = blockIdx.x, j = threadIdx.x;
    float cnt = fmaxf((float)(starts[g + 1] - starts[g]), 1.0f);
    pl[j] = psum[(g << 7) + j] / cnt;
    __syncthreads();
    float s = b1[j];
#pragma unroll 8
    for (int k = 0; k < DH; ++k)
        s = fmaf(pl[k], w1[(k << 7) + j], s);
    red[j] = fmaxf(s, 0.0f) * w2[j];
    __syncthreads();
    for (int st = 64; st > 0; st >>= 1) {
        if (j < st) red[j] += red[j + st];
        __syncthreads();
    }
    if (j == 0) out[g] = red[0] + b2[0];
}

extern "C" void kernel_launch(void* const* d_in, const int* in_sizes, int n_in,
                              void* d_out, int out_size, void* d_ws, size_t ws_size,
                              hipStream_t stream) {
    const float* x      = (const float*)d_in[0];
    const int*   ei     = (const int*)d_in[1];
    const int*   batch  = (const int*)d_in[2];
    const float* conv_w = (const float*)d_in[3];
    // d_in[4] = conv_b: cancels inside BatchNorm -> unused
    const float* bn_g   = (const float*)d_in[5];
    const float* bn_b   = (const float*)d_in[6];
    const float* w1     = (const float*)d_in[7];
    const float* b1     = (const float*)d_in[8];
    const float* w2     = (const float*)d_in[9];
    const float* b2     = (const float*)d_in[10];
    const int* src = ei;
    const int* dst = ei + NE;

    unsigned short* sbf       = (unsigned short*)d_ws;      // NN*DH bf16 (agg out / GEMM A)
    unsigned short* xbf       = sbf + (size_t)NN * DH;      // NN*DH bf16 (features Y)
    unsigned short* xdbf      = xbf + (size_t)NN * DH;      // NN*DH bf16 (XD = dinv*f(Y))
    unsigned short* wpack     = xdbf + (size_t)NN * DH;     // NL*DH*DH bf16
    float*          dinv      = (float*)(wpack + NL * DH * DH);  // NN
    float*          stats     = dinv + NN;                  // 256
    float*          psum      = stats + 256;                // NG*DH
    int*            starts    = (int*)(psum + NG * DH);     // 72
    int*            cnt       = starts + 72;                // NN
    int*            off       = cnt + NN;                   // NN
    int*            bucketcnt = off + NN;                   // 256 (NB used)
    int*            bucketoff = bucketcnt + 256;            // 256 (NB+1 used)
    int*            gcursor   = bucketoff + 256;            // 256
    float*          idsc      = (float*)(gcursor + 256);    // 256
    float*          bnsc      = idsc + 256;                 // 256
    int*            edata     = (int*)(bnsc + 256);         // NE int (12.8 MB)
    uint2*          tmp       = (uint2*)sbf;                // NE uint2, aliases sbf
                                                            // (dead until layer 0)

    // one-time: CSR build (phase-ordered) + input/weight bf16 conversion
    k_zero   <<<(NN + 255) / 256, 256, 0, stream>>>(bucketcnt, idsc, psum);
    k_convert<<<(NN * DH / 4 + 255) / 256, 256, 0, stream>>>(x, (ushort4*)xbf);
    k_wconv  <<<(NL * DH * DH + 255) / 256, 256, 0, stream>>>(conv_w, wpack);
    k_hist   <<<NE / EBLK_H, 256, 0, stream>>>(dst, bucketcnt);
    k_scan   <<<1, 256, 0, stream>>>(bucketcnt, bucketoff, gcursor);
    k_bin    <<<NE / EBLK, 256, 0, stream>>>(src, dst, gcursor, tmp);
    k_csr    <<<NB, 512, 0, stream>>>(tmp, bucketoff, cnt, dinv, off, edata);
    k_starts <<<(NN + 255) / 256, 256, 0, stream>>>(batch, starts);

    const float* SC = idsc;
    float lo = NEG_INF;  // layer 0: no BN, no ReLU on raw input
    for (int l = 0; l < NL; ++l) {
        k_prep     <<<12500, 256, 0, stream>>>(xbf, dinv, SC, lo, xdbf, stats);
        k_aggregate<<<25000, 256, 0, stream>>>(xdbf, edata, off, cnt, dinv, sbf);
        k_gemm_mfma<<<(NN + 127) / 128, 256, 0, stream>>>(
            sbf, wpack + (size_t)l * DH * DH, xbf, stats);
        k_bnprep   <<<1, 128, 0, stream>>>(stats, bn_g + l * DH, bn_b + l * DH, bnsc);
        SC = bnsc; lo = 0.0f;
    }
    k_pool_partial<<<(NN + 127) / 128, 128, 0, stream>>>(xbf, batch, bnsc, psum);
    k_mlp<<<NG, 128, 0, stream>>>(psum, starts, w1, b1, w2, b2, (float*)d_out);
}

// Round 11
// 774.952 us; speedup vs baseline: 1.2036x; 1.2036x over previous
//
#include <hip/hip_runtime.h>
#include <hip/hip_bf16.h>

#define NN 100000
#define NE 3200000
#define DH 128
#define NL 3
#define NG 64
#define BN_EPS 1e-5f
#define NEG_INF (-1e30f)
#define BSH 9                 // bucket = 512 consecutive dst nodes
#define NB 196                // ceil(NN / 512)
#define EBLK 12800            // edges per k_bin block (NE = 250 * EBLK)
#define EBLK_H 3200           // edges per k_hist block (NE = 1000 * EBLK_H)

typedef short bf16x8 __attribute__((ext_vector_type(8)));
typedef float f32x4  __attribute__((ext_vector_type(4)));

__device__ __forceinline__ void atomAddF(float* p, float v) {
    __hip_atomic_fetch_add(p, v, __ATOMIC_RELAXED, __HIP_MEMORY_SCOPE_AGENT);
}
__device__ __forceinline__ int atomAddI(int* p, int v) {
    return __hip_atomic_fetch_add(p, v, __ATOMIC_RELAXED, __HIP_MEMORY_SCOPE_AGENT);
}
// f32 -> bf16 round-to-nearest-even
__device__ __forceinline__ unsigned short bf16rn(float f) {
    unsigned int u = __float_as_uint(f);
    u += 0x7FFFu + ((u >> 16) & 1u);
    return (unsigned short)(u >> 16);
}
__device__ __forceinline__ float bf_lo(unsigned int u) { return __uint_as_float(u << 16); }
__device__ __forceinline__ float bf_hi(unsigned int u) { return __uint_as_float(u & 0xFFFF0000u); }
__device__ __forceinline__ float bfu(unsigned short u) {
    return __uint_as_float(((unsigned int)u) << 16);
}

__global__ void k_zero(int* __restrict__ bucketcnt, float* __restrict__ idsc,
                       float* __restrict__ psum) {
    int i = blockIdx.x * 256 + threadIdx.x;
    if (i < NB) bucketcnt[i] = 0;
    if (i < 2 * DH) idsc[i] = (i < DH) ? 1.0f : 0.0f;  // identity scale/shift
    if (i < NG * DH) psum[i] = 0.0f;
}

// one-time: x (f32) -> bf16 feature buffer
__global__ void k_convert(const float* __restrict__ X, ushort4* __restrict__ XB) {
    int i = blockIdx.x * 256 + threadIdx.x;
    if (i >= NN * DH / 4) return;
    float4 v = ((const float4*)X)[i];
    ushort4 o;
    o.x = bf16rn(v.x); o.y = bf16rn(v.y); o.z = bf16rn(v.z); o.w = bf16rn(v.w);
    XB[i] = o;
}

// one-time: W (f32 [l][k][n]) -> bf16 MFMA-fragment-contiguous pack:
// Wpack[l][ks][col][j] = W[l][ks*32+j][col]
__global__ void k_wconv(const float* __restrict__ W, unsigned short* __restrict__ WP) {
    int tid = blockIdx.x * 256 + threadIdx.x;
    if (tid >= NL * 16384) return;
    int l = tid >> 14;
    int p = tid & 16383;
    int ks = p >> 12;
    int col = (p >> 5) & 127;
    int j = p & 31;
    WP[tid] = bf16rn(W[l * 16384 + (ks * 32 + j) * 128 + col]);
}

// per-bucket edge histogram
__global__ __launch_bounds__(256) void k_hist(const int* __restrict__ dst,
                                              int* __restrict__ bucketcnt) {
    __shared__ int hist[NB];
    int t = threadIdx.x;
    if (t < NB) hist[t] = 0;
    __syncthreads();
    int base = blockIdx.x * EBLK_H;
    for (int i = t; i < EBLK_H; i += 256)
        atomicAdd(&hist[dst[base + i] >> BSH], 1);
    __syncthreads();
    if (t < NB && hist[t]) atomAddI(&bucketcnt[t], hist[t]);
}

// single block: exclusive scan of bucket counts
__global__ void k_scan(const int* __restrict__ bucketcnt, int* __restrict__ bucketoff,
                       int* __restrict__ gcursor) {
    __shared__ int s[256];
    int t = threadIdx.x;
    s[t] = (t < NB) ? bucketcnt[t] : 0;
    __syncthreads();
    for (int d = 1; d < 256; d <<= 1) {
        int v = (t >= d) ? s[t - d] : 0;
        __syncthreads();
        s[t] += v;
        __syncthreads();
    }
    if (t < NB) {
        int excl = s[t] - bucketcnt[t];
        bucketoff[t] = excl;
        gcursor[t] = excl;
    }
    if (t == NB - 1) bucketoff[NB] = s[t];
}

// bin edges into bucket-major order; records packed to 4B: (src<<9)|dst_local
__global__ __launch_bounds__(256) void k_bin(const int* __restrict__ src,
        const int* __restrict__ dst, int* __restrict__ gcursor,
        unsigned int* __restrict__ tmp) {
    __shared__ int hist[NB], cur[NB];
    int t = threadIdx.x;
    if (t < NB) hist[t] = 0;
    __syncthreads();
    int base = blockIdx.x * EBLK;
    for (int i = t; i < EBLK; i += 256)
        atomicAdd(&hist[dst[base + i] >> BSH], 1);
    __syncthreads();
    if (t < NB) cur[t] = hist[t] ? atomAddI(&gcursor[t], hist[t]) : 0;
    __syncthreads();
    for (int i = t; i < EBLK; i += 256) {
        int d = dst[base + i], s = src[base + i];
        int pos = atomicAdd(&cur[d >> BSH], 1);
        tmp[pos] = ((unsigned)s << BSH) | (unsigned)(d & ((1 << BSH) - 1));
    }
}

// one block per bucket: LDS histogram -> cnt/off/dinv; single-pass scatter of
// src into per-node CSR lists (writes confined to one bucket slice).
__global__ __launch_bounds__(512) void k_csr(const unsigned int* __restrict__ tmp,
        const int* __restrict__ bucketoff, int* __restrict__ cnt,
        float* __restrict__ dinv, int* __restrict__ off,
        int* __restrict__ edata) {
    __shared__ int lcnt[512];
    __shared__ int sc[512];
    int b = blockIdx.x, t = threadIdx.x;
    int nbase = b << BSH;
    int boff = bucketoff[b];
    int m = bucketoff[b + 1] - boff;
    lcnt[t] = 0;
    __syncthreads();
    for (int i = t; i < m; i += 512)
        atomicAdd(&lcnt[tmp[boff + i] & 511u], 1);
    __syncthreads();
    int c = lcnt[t];
    sc[t] = c;
    __syncthreads();
    for (int d = 1; d < 512; d <<= 1) {
        int v = (t >= d) ? sc[t - d] : 0;
        __syncthreads();
        sc[t] += v;
        __syncthreads();
    }
    int o = boff + sc[t] - c;
    int node = nbase + t;
    if (node < NN) {
        cnt[node] = c;
        off[node] = o;
        dinv[node] = rsqrtf((float)c + 1.0f);  // +1 self-loop
    }
    lcnt[t] = o;  // reuse as scatter cursor
    __syncthreads();
    for (int i = t; i < m; i += 512) {
        unsigned int r = tmp[boff + i];
        int pos = atomicAdd(&lcnt[r & 511u], 1);
        edata[pos] = (int)(r >> BSH);
    }
}

__global__ void k_starts(const int* __restrict__ batch, int* __restrict__ starts) {
    int i = blockIdx.x * 256 + threadIdx.x;
    if (i >= NN) return;
    int g  = batch[i];
    int gp = (i == 0) ? -1 : batch[i - 1];
    for (int gg = gp + 1; gg <= g; ++gg) starts[gg] = i;
    if (i == NN - 1) {
        for (int gg = g + 1; gg <= NG; ++gg) starts[gg] = NN;
    }
}

// per-layer prepass: XD[s] = bf16( dinv[s] * relu(BN(Y[s])) ); zeroes stats.
__global__ __launch_bounds__(256) void k_prep(const unsigned short* __restrict__ Y,
        const float* __restrict__ dinv, const float* __restrict__ SC, float lo,
        unsigned short* __restrict__ XD, float* __restrict__ stats) {
    int i = blockIdx.x * 256 + threadIdx.x;  // uint2 = 4 bf16 per thread
    if (blockIdx.x == 0 && threadIdx.x < 256) stats[threadIdx.x] = 0.0f;
    if (i >= NN * DH / 4) return;
    int row = i >> 5;
    int c4 = (i & 31) << 2;
    float di = dinv[row];
    uint2 u = ((const uint2*)Y)[i];
    float4 sc = *(const float4*)&SC[c4];
    float4 sh = *(const float4*)&SC[DH + c4];
    float f0 = di * fmaxf(fmaf(bf_lo(u.x), sc.x, sh.x), lo);
    float f1 = di * fmaxf(fmaf(bf_hi(u.x), sc.y, sh.y), lo);
    float f2 = di * fmaxf(fmaf(bf_lo(u.y), sc.z, sh.z), lo);
    float f3 = di * fmaxf(fmaf(bf_hi(u.y), sc.w, sh.w), lo);
    uint2 o;
    o.x = (unsigned int)bf16rn(f0) | ((unsigned int)bf16rn(f1) << 16);
    o.y = (unsigned int)bf16rn(f2) | ((unsigned int)bf16rn(f3) << 16);
    ((uint2*)XD)[i] = o;
}

// One wave per dst node: pure gather-add of XD rows,
// S[d] = dinv[d] * (sum XD[src] + XD[d]), packed bf16 store.
__global__ __launch_bounds__(256) void k_aggregate(const unsigned short* __restrict__ XD,
        const int* __restrict__ ed, const int* __restrict__ off,
        const int* __restrict__ cnt, const float* __restrict__ dinv,
        unsigned short* __restrict__ SB) {
    int w = (blockIdx.x << 2) + (threadIdx.x >> 6);  // 4 waves/block
    if (w >= NN) return;
    int lane = threadIdx.x & 63;
    int o = __builtin_amdgcn_readfirstlane(off[w]);
    int n = __builtin_amdgcn_readfirstlane(cnt[w]);
    const int* e = ed + o;
    int col = lane << 1;
    float ax = 0.0f, ay = 0.0f;
    int j = 0;
    for (; j + 8 <= n; j += 8) {
        int s0 = e[j], s1 = e[j+1], s2 = e[j+2], s3 = e[j+3];
        int s4 = e[j+4], s5 = e[j+5], s6 = e[j+6], s7 = e[j+7];
        unsigned int u0 = *(const unsigned int*)&XD[(size_t)s0 * DH + col];
        unsigned int u1 = *(const unsigned int*)&XD[(size_t)s1 * DH + col];
        unsigned int u2 = *(const unsigned int*)&XD[(size_t)s2 * DH + col];
        unsigned int u3 = *(const unsigned int*)&XD[(size_t)s3 * DH + col];
        unsigned int u4 = *(const unsigned int*)&XD[(size_t)s4 * DH + col];
        unsigned int u5 = *(const unsigned int*)&XD[(size_t)s5 * DH + col];
        unsigned int u6 = *(const unsigned int*)&XD[(size_t)s6 * DH + col];
        unsigned int u7 = *(const unsigned int*)&XD[(size_t)s7 * DH + col];
        ax += bf_lo(u0); ay += bf_hi(u0);
        ax += bf_lo(u1); ay += bf_hi(u1);
        ax += bf_lo(u2); ay += bf_hi(u2);
        ax += bf_lo(u3); ay += bf_hi(u3);
        ax += bf_lo(u4); ay += bf_hi(u4);
        ax += bf_lo(u5); ay += bf_hi(u5);
        ax += bf_lo(u6); ay += bf_hi(u6);
        ax += bf_lo(u7); ay += bf_hi(u7);
    }
    for (; j < n; ++j) {
        unsigned int u0 = *(const unsigned int*)&XD[(size_t)e[j] * DH + col];
        ax += bf_lo(u0); ay += bf_hi(u0);
    }
    unsigned int us = *(const unsigned int*)&XD[(size_t)w * DH + col];
    float di = dinv[w];
    float ox = di * (ax + bf_lo(us));
    float oy = di * (ay + bf_hi(us));
    unsigned int up = (unsigned int)bf16rn(ox) | ((unsigned int)bf16rn(oy) << 16);
    *(unsigned int*)&SB[(size_t)w * DH + col] = up;
}

// MFMA GEMM: Y = S(bf16) @ W(bf16), f32 accum; bf16 out + BN stats.
__global__ __launch_bounds__(256) void k_gemm_mfma(const unsigned short* __restrict__ A,
        const unsigned short* __restrict__ WP, unsigned short* __restrict__ YB,
        float* __restrict__ stats) {
    __shared__ unsigned short ctile[128 * 132];  // 33 KB
    int t = threadIdx.x;
    int lane = t & 63, wid = t >> 6;
    int wr = wid >> 1, wc = wid & 1;
    int lr = lane & 15, lg = lane >> 4;
    int row0 = blockIdx.x * 128;
    f32x4 acc[4][4] = {};
#pragma unroll
    for (int ks = 0; ks < 4; ++ks) {
        bf16x8 a[4], b[4];
        const unsigned short* abase =
            A + (size_t)(row0 + wr * 64 + lr) * DH + ks * 32 + lg * 8;
#pragma unroll
        for (int rb = 0; rb < 4; ++rb)
            a[rb] = *(const bf16x8*)(abase + (size_t)rb * 16 * DH);
        const unsigned short* bbase = WP + ks * 4096 + (wc * 64 + lr) * 32 + lg * 8;
#pragma unroll
        for (int cb = 0; cb < 4; ++cb)
            b[cb] = *(const bf16x8*)(bbase + cb * 16 * 32);
#pragma unroll
        for (int rb = 0; rb < 4; ++rb)
#pragma unroll
            for (int cb = 0; cb < 4; ++cb)
                acc[rb][cb] = __builtin_amdgcn_mfma_f32_16x16x32_bf16(
                    a[rb], b[cb], acc[rb][cb], 0, 0, 0);
    }
    // C/D layout: col = lane&15, row = (lane>>4)*4 + reg
#pragma unroll
    for (int rb = 0; rb < 4; ++rb)
#pragma unroll
        for (int cb = 0; cb < 4; ++cb)
#pragma unroll
            for (int r = 0; r < 4; ++r) {
                int row = wr * 64 + rb * 16 + lg * 4 + r;
                int col = wc * 64 + cb * 16 + lr;
                ctile[row * 132 + col] = bf16rn(acc[rb][cb][r]);
            }
    __syncthreads();
    int c4 = (t & 31) << 2;
    int r0l = t >> 5;
    float ps[4] = {}, q[4] = {};
#pragma unroll
    for (int i = 0; i < 16; ++i) {
        int rl = r0l + (i << 3);
        int r = row0 + rl;
        if (r < NN) {
            ushort4 v = *(const ushort4*)&ctile[rl * 132 + c4];
            *(ushort4*)&YB[(size_t)r * DH + c4] = v;
            float f0 = bfu(v.x), f1 = bfu(v.y), f2 = bfu(v.z), f3 = bfu(v.w);
            ps[0] += f0; ps[1] += f1; ps[2] += f2; ps[3] += f3;
            q[0] = fmaf(f0, f0, q[0]); q[1] = fmaf(f1, f1, q[1]);
            q[2] = fmaf(f2, f2, q[2]); q[3] = fmaf(f3, f3, q[3]);
        }
    }
    __syncthreads();  // ctile dead; reuse as reduction scratch
    float* red = (float*)ctile;
    int base = t * 8;
    red[base + 0] = ps[0]; red[base + 1] = ps[1]; red[base + 2] = ps[2]; red[base + 3] = ps[3];
    red[base + 4] = q[0];  red[base + 5] = q[1];  red[base + 6] = q[2];  red[base + 7] = q[3];
    __syncthreads();
    if (t < 32) {
        float s[8] = {};
        for (int g2 = 0; g2 < 8; ++g2) {
            int b2 = (g2 * 32 + t) * 8;
#pragma unroll
            for (int j = 0; j < 8; ++j) s[j] += red[b2 + j];
        }
        int cc = t << 2;
        atomAddF(&stats[cc + 0], s[0]); atomAddF(&stats[cc + 1], s[1]);
        atomAddF(&stats[cc + 2], s[2]); atomAddF(&stats[cc + 3], s[3]);
        atomAddF(&stats[DH + cc + 0], s[4]); atomAddF(&stats[DH + cc + 1], s[5]);
        atomAddF(&stats[DH + cc + 2], s[6]); atomAddF(&stats[DH + cc + 3], s[7]);
    }
}

// stats -> per-channel scale/shift for fused BN
__global__ void k_bnprep(const float* __restrict__ stats, const float* __restrict__ gamma,
                         const float* __restrict__ beta, float* __restrict__ SC) {
    int j = threadIdx.x;
    if (j >= DH) return;
    const float inv_n = 1.0f / NN;
    float mean = stats[j] * inv_n;
    float var  = stats[DH + j] * inv_n - mean * mean;
    float s    = gamma[j] * rsqrtf(var + BN_EPS);
    SC[j] = s;
    SC[DH + j] = beta[j] - mean * s;
}

// Parallel pool over bf16 features: BN+ReLU inline; atomic flush at graph
// boundaries only (batch sorted).
__global__ __launch_bounds__(128) void k_pool_partial(const unsigned short* __restrict__ HB,
        const int* __restrict__ batch, const float* __restrict__ SC,
        float* __restrict__ psum) {
    __shared__ int bsh[128];
    int t = threadIdx.x;
    int row0 = blockIdx.x * 128;
    int rl = row0 + t;
    bsh[t] = batch[rl < NN ? rl : (NN - 1)];
    __syncthreads();
    int ro = t >> 5;
    int c  = (t & 31) << 2;
    float4 sc = *(const float4*)&SC[c];
    float4 sh = *(const float4*)&SC[DH + c];
    int nrows = NN - row0; if (nrows > 128) nrows = 128;
    float4 acc = make_float4(0.f, 0.f, 0.f, 0.f);
    int cur = -1;
    for (int rr = ro; rr < nrows; rr += 4) {
        int g = bsh[rr];
        if (g != cur) {
            if (cur >= 0) {
                float* p = &psum[(cur << 7) + c];
                atomAddF(p + 0, acc.x); atomAddF(p + 1, acc.y);
                atomAddF(p + 2, acc.z); atomAddF(p + 3, acc.w);
            }
            acc = make_float4(0.f, 0.f, 0.f, 0.f);
            cur = g;
        }
        uint2 u = *(const uint2*)&HB[(size_t)(row0 + rr) * DH + c];
        acc.x += fmaxf(fmaf(bf_lo(u.x), sc.x, sh.x), 0.0f);
        acc.y += fmaxf(fmaf(bf_hi(u.x), sc.y, sh.y), 0.0f);
        acc.z += fmaxf(fmaf(bf_lo(u.y), sc.z, sh.z), 0.0f);
        acc.w += fmaxf(fmaf(bf_hi(u.y), sc.w, sh.w), 0.0f);
    }
    if (cur >= 0) {
        float* p = &psum[(cur << 7) + c];
        atomAddF(p + 0, acc.x); atomAddF(p + 1, acc.y);
        atomAddF(p + 2, acc.z); atomAddF(p + 3, acc.w);
    }
}

// One block per graph: divide by count, hidden GEMV, reduce to scalar output.
__global__ __launch_bounds__(128) void k_mlp(const float* __restrict__ psum,
        const int* __restrict__ starts, const float* __restrict__ w1,
        const float* __restrict__ b1, const float* __restrict__ w2,
        const float* __restrict__ b2, float* __restrict__ out) {
    __shared__ float pl[DH];
    __shared__ float red[DH];
    int g = blockIdx.x, j = threadIdx.x;
    float cnt = fmaxf((float)(starts[g + 1] - starts[g]), 1.0f);
    pl[j] = psum[(g << 7) + j] / cnt;
    __syncthreads();
    float s = b1[j];
#pragma unroll 8
    for (int k = 0; k < DH; ++k)
        s = fmaf(pl[k], w1[(k << 7) + j], s);
    red[j] = fmaxf(s, 0.0f) * w2[j];
    __syncthreads();
    for (int st = 64; st > 0; st >>= 1) {
        if (j < st) red[j] += red[j + st];
        __syncthreads();
    }
    if (j == 0) out[g] = red[0] + b2[0];
}

extern "C" void kernel_launch(void* const* d_in, const int* in_sizes, int n_in,
                              void* d_out, int out_size, void* d_ws, size_t ws_size,
                              hipStream_t stream) {
    const float* x      = (const float*)d_in[0];
    const int*   ei     = (const int*)d_in[1];
    const int*   batch  = (const int*)d_in[2];
    const float* conv_w = (const float*)d_in[3];
    // d_in[4] = conv_b: cancels inside BatchNorm -> unused
    const float* bn_g   = (const float*)d_in[5];
    const float* bn_b   = (const float*)d_in[6];
    const float* w1     = (const float*)d_in[7];
    const float* b1     = (const float*)d_in[8];
    const float* w2     = (const float*)d_in[9];
    const float* b2     = (const float*)d_in[10];
    const int* src = ei;
    const int* dst = ei + NE;

    unsigned short* sbf       = (unsigned short*)d_ws;      // NN*DH bf16 (agg out / GEMM A)
    unsigned short* xbf       = sbf + (size_t)NN * DH;      // NN*DH bf16 (features Y)
    unsigned short* xdbf      = xbf + (size_t)NN * DH;      // NN*DH bf16 (XD = dinv*f(Y))
    unsigned short* wpack     = xdbf + (size_t)NN * DH;     // NL*DH*DH bf16
    float*          dinv      = (float*)(wpack + NL * DH * DH);  // NN
    float*          stats     = dinv + NN;                  // 256
    float*          psum      = stats + 256;                // NG*DH
    int*            starts    = (int*)(psum + NG * DH);     // 72
    int*            cnt       = starts + 72;                // NN
    int*            off       = cnt + NN;                   // NN
    int*            bucketcnt = off + NN;                   // 256 (NB used)
    int*            bucketoff = bucketcnt + 256;            // 256 (NB+1 used)
    int*            gcursor   = bucketoff + 256;            // 256
    float*          idsc      = (float*)(gcursor + 256);    // 256
    float*          bnsc      = idsc + 256;                 // 256
    int*            edata     = (int*)(bnsc + 256);         // NE int (12.8 MB)
    unsigned int*   tmp       = (unsigned int*)sbf;         // NE uint (12.8 MB), aliases
                                                            // sbf (dead until layer 0)

    // one-time: CSR build + input/weight bf16 conversion
    k_zero   <<<(NN + 255) / 256, 256, 0, stream>>>(bucketcnt, idsc, psum);
    k_convert<<<(NN * DH / 4 + 255) / 256, 256, 0, stream>>>(x, (ushort4*)xbf);
    k_wconv  <<<(NL * DH * DH + 255) / 256, 256, 0, stream>>>(conv_w, wpack);
    k_hist   <<<NE / EBLK_H, 256, 0, stream>>>(dst, bucketcnt);
    k_scan   <<<1, 256, 0, stream>>>(bucketcnt, bucketoff, gcursor);
    k_bin    <<<NE / EBLK, 256, 0, stream>>>(src, dst, gcursor, tmp);
    k_csr    <<<NB, 512, 0, stream>>>(tmp, bucketoff, cnt, dinv, off, edata);
    k_starts <<<(NN + 255) / 256, 256, 0, stream>>>(batch, starts);

    const float* SC = idsc;
    float lo = NEG_INF;  // layer 0: no BN, no ReLU on raw input
    for (int l = 0; l < NL; ++l) {
        k_prep     <<<12500, 256, 0, stream>>>(xbf, dinv, SC, lo, xdbf, stats);
        k_aggregate<<<25000, 256, 0, stream>>>(xdbf, edata, off, cnt, dinv, sbf);
        k_gemm_mfma<<<(NN + 127) / 128, 256, 0, stream>>>(
            sbf, wpack + (size_t)l * DH * DH, xbf, stats);
        k_bnprep   <<<1, 128, 0, stream>>>(stats, bn_g + l * DH, bn_b + l * DH, bnsc);
        SC = bnsc; lo = 0.0f;
    }
    k_pool_partial<<<(NN + 127) / 128, 128, 0, stream>>>(xbf, batch, bnsc, psum);
    k_mlp<<<NG, 128, 0, stream>>>(psum, starts, w1, b1, w2, b2, (float*)d_out);
}